// Round 2
// baseline (359.977 us; speedup 1.0000x reference)
//
#include <hip/hip_runtime.h>

#define B_ 8
#define S_ 2048
#define IN_ 4096
#define OUT_ 4096
#define R_ 16
#define E_ 64

__device__ __forceinline__ float dot4(float4 a, float4 b) {
  return a.x*b.x + a.y*b.y + a.z*b.z + a.w*b.w;
}

// wave-parallel top-16 (descending, ties -> lower index, matching lax.top_k)
__device__ __forceinline__ void topk16(float v, int* __restrict__ dst) {
  const int lane = threadIdx.x & 63;
  for (int r = 0; r < R_; ++r) {
    float mv = v; int mi = lane;
    #pragma unroll
    for (int off = 1; off < 64; off <<= 1) {
      float v2 = __shfl_xor(mv, off, 64);
      int   i2 = __shfl_xor(mi, off, 64);
      if (v2 > mv || (v2 == mv && i2 < mi)) { mv = v2; mi = i2; }
    }
    if (lane == 0) dst[r] = mi;
    if (lane == mi) v = -__builtin_inff();
  }
}

// ---------------- K1: gating scores + top-k for A (1 block per batch) --------
__global__ __launch_bounds__(256) void k_gate(
    const float* __restrict__ q, const float* __restrict__ W_rA,
    const float* __restrict__ b_rA, const float* __restrict__ W_rB,
    const float* __restrict__ b_rB, float* __restrict__ gB0,
    int* __restrict__ idxA)
{
  const int b = blockIdx.x;
  __shared__ float qs[IN_];
  __shared__ float sA[E_];
  const int tid = threadIdx.x;
  {
    const float4* q4 = (const float4*)(q + (size_t)b * IN_);
    float4* s4 = (float4*)qs;
    for (int i = tid; i < IN_ / 4; i += 256) s4[i] = q4[i];
  }
  __syncthreads();
  const int wave = tid >> 6, lane = tid & 63;
  const float4* qs4 = (const float4*)qs;
  for (int k = 0; k < 16; ++k) {
    const int e = wave * 16 + k;
    const float4* wa = (const float4*)(W_rA + (size_t)e * IN_);
    const float4* wb = (const float4*)(W_rB + (size_t)e * IN_);
    float pa = 0.f, pb = 0.f;
    for (int i = lane; i < IN_ / 4; i += 64) {
      float4 qv = qs4[i];
      pa += dot4(qv, wa[i]);
      pb += dot4(qv, wb[i]);
    }
    #pragma unroll
    for (int off = 1; off < 64; off <<= 1) {
      pa += __shfl_xor(pa, off, 64);
      pb += __shfl_xor(pb, off, 64);
    }
    if (lane == 0) {
      sA[e] = pa + b_rA[e];
      gB0[b * E_ + e] = pb + b_rB[e];
    }
  }
  __syncthreads();
  if (tid < 64) topk16(sA[tid], idxA + b * R_);
}

// ---------------- K2: cfs einsum partials (reads cfs_W exactly once) ---------
// grid 128 = r(16) x ic(8 chunks of 512 over IN)
__global__ __launch_bounds__(256) void k_cfs(
    const float* __restrict__ A_pool, const float* __restrict__ cfs,
    const int* __restrict__ idxA, float* __restrict__ gBpart)
{
  const int blk = blockIdx.x;
  const int r = blk >> 3, ic = blk & 7;
  __shared__ float as[B_][512];
  __shared__ float red[4][B_][E_];
  const int tid = threadIdx.x;
  {
    const int b = tid >> 5, t = tid & 31;
    const int e = idxA[b * R_ + r];
    const float4* src = (const float4*)(A_pool + ((size_t)e * R_ + r) * IN_ + ic * 512);
    float4* dst = (float4*)as[b];
    for (int j = t; j < 128; j += 32) dst[j] = src[j];
  }
  __syncthreads();
  const int e = tid & 63, part = tid >> 6;
  float acc[B_];
  #pragma unroll
  for (int b = 0; b < B_; ++b) acc[b] = 0.f;
  const float* cbase = cfs + ((size_t)r * IN_ + ic * 512) * E_ + e;
  for (int i = part * 128; i < part * 128 + 128; ++i) {
    float c = cbase[(size_t)i * E_];
    #pragma unroll
    for (int b = 0; b < B_; ++b) acc[b] += as[b][i] * c;
  }
  #pragma unroll
  for (int b = 0; b < B_; ++b) red[part][b][e] = acc[b];
  __syncthreads();
  if (tid < 64) {
    #pragma unroll
    for (int b = 0; b < B_; ++b)
      gBpart[((size_t)blk * B_ + b) * E_ + tid] =
          red[0][b][tid] + red[1][b][tid] + red[2][b][tid] + red[3][b][tid];
  }
}

__global__ __launch_bounds__(64) void k_topk_b(
    const float* __restrict__ gB0, const float* __restrict__ gBpart,
    int* __restrict__ idxB)
{
  const int b = blockIdx.x;
  const int lane = threadIdx.x & 63;
  float v = gB0[b * E_ + lane];
  for (int blk = 0; blk < 128; ++blk)
    v += gBpart[((size_t)blk * B_ + b) * E_ + lane];
  topk16(v, idxB + b * R_);
}

// ---------------- K3: pack lora_B (strided gather -> coalesced layout) -------
__global__ __launch_bounds__(256) void k_pack_b(
    const float* __restrict__ B_pool, const int* __restrict__ idxB,
    float* __restrict__ loraBp)
{
  const int blk = blockIdx.x;            // 128 = b*16 + r
  const int b = blk >> 4, r = blk & 15;
  const int e = idxB[b * R_ + r];
  const float* src = B_pool + (size_t)e * OUT_ * R_ + r;
  float* dst = loraBp + (size_t)(b * R_ + r) * OUT_;
  for (int o = threadIdx.x; o < OUT_; o += 256) dst[o] = src[(size_t)o * R_];
}

// ---------------- K4: fused after_A + expansion -------------------------------
// grid 512 = b(8) x rt(64 tiles of 32 rows). Phase 1: after_A tile (32x16) with
// full-K accumulation (A chunks in LDS, x streamed, 16 loads issued up-front).
// Phase 2: tile @ lora_Bp with coalesced float4 stores.
__global__ __launch_bounds__(256) void k_fused(
    const float* __restrict__ x, const float* __restrict__ A_pool,
    const int* __restrict__ idxA, const float* __restrict__ loraBp,
    float* __restrict__ out)
{
  const int bx = blockIdx.x;
  const int b = bx >> 6, rt = bx & 63;
  const int row0 = rt * 32;
  __shared__ float4 As[R_][128];   // 16 x 512 floats = 32 KB
  __shared__ float aa[32][R_];     // 2 KB
  const int tid = threadIdx.x;
  const int rg = tid >> 5, p = tid & 31;
  // A staging: thread (sr, stt) stages row sr, float4s stt, stt+16, ...
  const int sr = tid >> 4, stt = tid & 15;
  const size_t arow = ((size_t)idxA[b * R_ + sr] * R_ + sr) * IN_;
  const float* xbase = x + ((size_t)b * S_ + row0 + rg * 4) * IN_;

  float acc[4][R_];
  #pragma unroll
  for (int m = 0; m < 4; ++m)
    #pragma unroll
    for (int r = 0; r < R_; ++r) acc[m][r] = 0.f;

  for (int ks = 0; ks < 8; ++ks) {
    if (ks) __syncthreads();  // previous chunk's compute done before overwrite
    {
      const float4* src = (const float4*)(A_pool + arow + ks * 512);
      #pragma unroll
      for (int j = stt; j < 128; j += 16) As[sr][j] = src[j];
    }
    // issue all 16 x loads for this chunk before the barrier
    float4 xv[4][4];
    const float* xb = xbase + ks * 512;
    #pragma unroll
    for (int st = 0; st < 4; ++st) {
      const int i4 = st * 32 + p;
      #pragma unroll
      for (int m = 0; m < 4; ++m)
        xv[st][m] = *(const float4*)(xb + (size_t)m * IN_ + i4 * 4);
    }
    __syncthreads();
    #pragma unroll
    for (int st = 0; st < 4; ++st) {
      const int i4 = st * 32 + p;
      #pragma unroll
      for (int r = 0; r < R_; ++r) {
        float4 a = As[r][i4];
        #pragma unroll
        for (int m = 0; m < 4; ++m)
          acc[m][r] += dot4(xv[st][m], a);
      }
    }
  }
  // reduce across the 32 p-lanes (p = lane bits 0..4, stays within wave halves)
  #pragma unroll
  for (int m = 0; m < 4; ++m)
    #pragma unroll
    for (int r = 0; r < R_; ++r) {
      float v = acc[m][r];
      v += __shfl_xor(v, 1, 64);
      v += __shfl_xor(v, 2, 64);
      v += __shfl_xor(v, 4, 64);
      v += __shfl_xor(v, 8, 64);
      v += __shfl_xor(v, 16, 64);
      acc[m][r] = v;
    }
  if (p == 0) {
    #pragma unroll
    for (int m = 0; m < 4; ++m)
      #pragma unroll
      for (int r = 0; r < R_; ++r) aa[rg * 4 + m][r] = acc[m][r];
  }
  __syncthreads();

  // Phase 2: out[row0..row0+31][:] = aa @ lora_Bp[b]
  #pragma unroll
  for (int oc = 0; oc < 4; ++oc) {
    float4 Bf[R_];
    #pragma unroll
    for (int r = 0; r < R_; ++r)
      Bf[r] = *(const float4*)(loraBp + (size_t)(b * R_ + r) * OUT_ + oc * 1024 + tid * 4);
    for (int s = 0; s < 32; ++s) {
      const float4* av = (const float4*)aa[s];
      float4 a0 = av[0], a1 = av[1], a2 = av[2], a3 = av[3];
      float4 o = make_float4(0.f, 0.f, 0.f, 0.f);
      o.x += a0.x*Bf[0].x;  o.y += a0.x*Bf[0].y;  o.z += a0.x*Bf[0].z;  o.w += a0.x*Bf[0].w;
      o.x += a0.y*Bf[1].x;  o.y += a0.y*Bf[1].y;  o.z += a0.y*Bf[1].z;  o.w += a0.y*Bf[1].w;
      o.x += a0.z*Bf[2].x;  o.y += a0.z*Bf[2].y;  o.z += a0.z*Bf[2].z;  o.w += a0.z*Bf[2].w;
      o.x += a0.w*Bf[3].x;  o.y += a0.w*Bf[3].y;  o.z += a0.w*Bf[3].z;  o.w += a0.w*Bf[3].w;
      o.x += a1.x*Bf[4].x;  o.y += a1.x*Bf[4].y;  o.z += a1.x*Bf[4].z;  o.w += a1.x*Bf[4].w;
      o.x += a1.y*Bf[5].x;  o.y += a1.y*Bf[5].y;  o.z += a1.y*Bf[5].z;  o.w += a1.y*Bf[5].w;
      o.x += a1.z*Bf[6].x;  o.y += a1.z*Bf[6].y;  o.z += a1.z*Bf[6].z;  o.w += a1.z*Bf[6].w;
      o.x += a1.w*Bf[7].x;  o.y += a1.w*Bf[7].y;  o.z += a1.w*Bf[7].z;  o.w += a1.w*Bf[7].w;
      o.x += a2.x*Bf[8].x;  o.y += a2.x*Bf[8].y;  o.z += a2.x*Bf[8].z;  o.w += a2.x*Bf[8].w;
      o.x += a2.y*Bf[9].x;  o.y += a2.y*Bf[9].y;  o.z += a2.y*Bf[9].z;  o.w += a2.y*Bf[9].w;
      o.x += a2.z*Bf[10].x; o.y += a2.z*Bf[10].y; o.z += a2.z*Bf[10].z; o.w += a2.z*Bf[10].w;
      o.x += a2.w*Bf[11].x; o.y += a2.w*Bf[11].y; o.z += a2.w*Bf[11].z; o.w += a2.w*Bf[11].w;
      o.x += a3.x*Bf[12].x; o.y += a3.x*Bf[12].y; o.z += a3.x*Bf[12].z; o.w += a3.x*Bf[12].w;
      o.x += a3.y*Bf[13].x; o.y += a3.y*Bf[13].y; o.z += a3.y*Bf[13].z; o.w += a3.y*Bf[13].w;
      o.x += a3.z*Bf[14].x; o.y += a3.z*Bf[14].y; o.z += a3.z*Bf[14].z; o.w += a3.z*Bf[14].w;
      o.x += a3.w*Bf[15].x; o.y += a3.w*Bf[15].y; o.z += a3.w*Bf[15].z; o.w += a3.w*Bf[15].w;
      *(float4*)(out + ((size_t)b * S_ + row0 + s) * OUT_ + oc * 1024 + tid * 4) = o;
    }
  }
}

// ---------------- launch ------------------------------------------------------
extern "C" void kernel_launch(void* const* d_in, const int* in_sizes, int n_in,
                              void* d_out, int out_size, void* d_ws, size_t ws_size,
                              hipStream_t stream) {
  const float* x      = (const float*)d_in[0];
  const float* qsig   = (const float*)d_in[1];
  const float* A_pool = (const float*)d_in[2];
  const float* B_pool = (const float*)d_in[3];
  const float* W_rA   = (const float*)d_in[4];
  const float* b_rA   = (const float*)d_in[5];
  const float* W_rB   = (const float*)d_in[6];
  const float* b_rB   = (const float*)d_in[7];
  const float* cfs_W  = (const float*)d_in[8];
  float* out = (float*)d_out;

  char* w = (char*)d_ws;
  int*   idxA    = (int*)(w);              // 256 B (pad 512)
  int*   idxB    = (int*)(w + 512);        // 256 B
  float* gB0     = (float*)(w + 1024);     // 2 KB
  float* gBpart  = (float*)(w + 3072);     // 128*8*64*4 = 256 KB
  float* loraBp  = (float*)(w + 265216);   // 8*16*4096*4 = 2 MB

  k_gate<<<8, 256, 0, stream>>>(qsig, W_rA, b_rA, W_rB, b_rB, gB0, idxA);
  k_cfs<<<128, 256, 0, stream>>>(A_pool, cfs_W, idxA, gBpart);
  k_topk_b<<<8, 64, 0, stream>>>(gB0, gBpart, idxB);
  k_pack_b<<<128, 256, 0, stream>>>(B_pool, idxB, loraBp);
  k_fused<<<512, 256, 0, stream>>>(x, A_pool, idxA, loraBp, out);
}